// Round 1
// baseline (351.334 us; speedup 1.0000x reference)
//
#include <hip/hip_runtime.h>
#include <hip/hip_bf16.h>

// sum(x) * a * b, x: 8192x8192 fp32. Memory-bound full reduction.

#define BLOCKS 2048
#define THREADS 256

__global__ __launch_bounds__(THREADS) void reduce_stage1(
    const float4* __restrict__ x4, size_t n4, float* __restrict__ partials) {
    float s = 0.0f;
    size_t stride = (size_t)gridDim.x * blockDim.x;
    for (size_t i = (size_t)blockIdx.x * blockDim.x + threadIdx.x; i < n4; i += stride) {
        float4 v = x4[i];
        s += (v.x + v.y) + (v.z + v.w);
    }
    // wave-64 reduction
    #pragma unroll
    for (int off = 32; off > 0; off >>= 1)
        s += __shfl_down(s, off, 64);
    __shared__ float lds[THREADS / 64];
    int wave = threadIdx.x >> 6;
    if ((threadIdx.x & 63) == 0) lds[wave] = s;
    __syncthreads();
    if (threadIdx.x == 0) {
        float t = 0.0f;
        #pragma unroll
        for (int w = 0; w < THREADS / 64; ++w) t += lds[w];
        partials[blockIdx.x] = t;
    }
}

__global__ __launch_bounds__(THREADS) void reduce_stage2(
    const float* __restrict__ partials, int nblocks,
    const float* __restrict__ a, const float* __restrict__ b,
    float* __restrict__ out) {
    float s = 0.0f;
    for (int i = threadIdx.x; i < nblocks; i += THREADS) s += partials[i];
    #pragma unroll
    for (int off = 32; off > 0; off >>= 1)
        s += __shfl_down(s, off, 64);
    __shared__ float lds[THREADS / 64];
    int wave = threadIdx.x >> 6;
    if ((threadIdx.x & 63) == 0) lds[wave] = s;
    __syncthreads();
    if (threadIdx.x == 0) {
        float t = 0.0f;
        #pragma unroll
        for (int w = 0; w < THREADS / 64; ++w) t += lds[w];
        out[0] = t * a[0] * b[0];
    }
}

extern "C" void kernel_launch(void* const* d_in, const int* in_sizes, int n_in,
                              void* d_out, int out_size, void* d_ws, size_t ws_size,
                              hipStream_t stream) {
    const float* x = (const float*)d_in[0];
    const float* a = (const float*)d_in[1];
    const float* b = (const float*)d_in[2];
    float* out = (float*)d_out;
    float* partials = (float*)d_ws;

    size_t n = (size_t)in_sizes[0];      // 67108864, divisible by 4
    size_t n4 = n / 4;

    reduce_stage1<<<BLOCKS, THREADS, 0, stream>>>((const float4*)x, n4, partials);
    reduce_stage2<<<1, THREADS, 0, stream>>>(partials, BLOCKS, a, b, out);
}